// Round 6
// baseline (229.937 us; speedup 1.0000x reference)
//
#include <hip/hip_runtime.h>

// Correlation / cost-volume, fp32.
// corr[b, dy*9+dx, y, x] = (1/128) * sum_c in1[b,c,y,x] * in2[b,c,y+dy-4,x+dx-4]
//
// R6: R5's inner loop (DPP x-halos, 2 ds_read_b128/ch, 72 FMA) but:
//  - TY=2 -> 320-thread blocks (5 waves), grid 512, 2 blocks/CU co-resident:
//    two independent barrier domains per CU hide each other's vmcnt drains.
//  - in1 ALSO staged via global_load_lds DMA (4 slots/chunk): the hot loop
//    has no register-destination global loads at all, so no exposed HBM
//    latency and nothing for the register allocator to serialize.
// Per chunk: 25 x 1-KB DMA slots (21 in2 + 4 in1), double-buffered;
// one barrier per chunk; chunk k+1's DMA issued before computing chunk k.

#define MAXD 4
#define ND 9
#define NDISP 81
#define BATCH 8
#define CH 128
#define HH 128
#define WW 128
#define HW (HH * WW)
#define CC 4                     // channels per chunk
#define NCHUNK (CH / CC)         // 32
#define TY 2
#define NROW (TY + 2 * MAXD)     // 10 staged in2 rows
#define PITCH 132                // 128 + 4 pad floats
#define CPC (NROW * PITCH)       // 1320 floats per in2 channel
#define IN2SLOTS 21              // ceil(4*1320/256)
#define IN1OFF (IN2SLOTS * 256)  // 5376: in1 region base (TY*CC*128=1024 f)
#define NSLOT 25                 // 21 in2 + 4 in1 1-KB DMA slots
#define CHFP (NSLOT * 256)       // 6400 floats per buffer
#define NT 320                   // 5 waves; threads 0..287 compute
#define NACT 288                 // (ly:2)(dy:9)(xg:16)

typedef const __attribute__((address_space(1))) float GAS;
typedef __attribute__((address_space(3))) float LAS;

__device__ __forceinline__ void dma16(const float* g, float* l) {
    __builtin_amdgcn_global_load_lds((GAS*)g, (LAS*)l, 16, 0, 0);
}
__device__ __forceinline__ float dpp_shr1(float x) {   // lane i <- lane i-1
    return __int_as_float(__builtin_amdgcn_update_dpp(
        0, __float_as_int(x), 0x111, 0xF, 0xF, true));
}
__device__ __forceinline__ float dpp_shl1(float x) {   // lane i <- lane i+1
    return __int_as_float(__builtin_amdgcn_update_dpp(
        0, __float_as_int(x), 0x101, 0xF, 0xF, true));
}

__global__ __launch_bounds__(NT, 2) void corr_kernel(
    const float* __restrict__ in1,
    const float* __restrict__ in2,
    float* __restrict__ out)
{
    __shared__ float s2[2][CHFP];   // 2 x 25600 B = 51200 B

    const int tid = threadIdx.x;
    const int b   = blockIdx.x;
    const int y0  = blockIdx.y * TY;

    const bool act = tid < NACT;
    const int xg   = tid & 15;              // 16 lanes span the 128-px row
    const int dy   = (tid >> 4) % ND;
    const int ly   = act ? (tid / 144) : 0; // clamp pads to valid addresses
    const int lane = tid & 63;
    const int rl   = ly + dy;               // staged in2 row consumed
    const bool rok = (unsigned)(y0 + rl - MAXD) < (unsigned)HH;

    const float* in1b = in1 + (size_t)b * CH * HW;
    const float* in2b = in2 + (size_t)b * CH * HW;

    // ---- DMA slot sources: 5 slots/wave, slot s = wv + it*5 ----
    const int wv = __builtin_amdgcn_readfirstlane(tid >> 6);   // 0..4
    const float* gsrc[5];
    #pragma unroll
    for (int it = 0; it < 5; ++it) {
        int s = wv + it * 5;
        if (s < IN2SLOTS) {
            // in2 region: flat F = s*256 + lane*4 -> [c][R][PITCH]
            int F = s * 256 + lane * 4;
            int c = F / CPC;
            int f = F - c * CPC;
            int R = f / PITCH;
            int j = f - R * PITCH;          // multiple of 4; >=128 => pad col
            bool v = (c < CC) && (j < WW);
            int rr = y0 - MAXD + R;
            int sr = rr < 0 ? 0 : (rr >= HH ? HH - 1 : rr);  // clamp: garbage
            gsrc[it] = in2b + (v ? ((size_t)c * HW + (size_t)sr * WW + j) : 0);
        } else {
            // in1 region: F = (s-21)*256 + lane*4 -> [ly][c][128]
            int F   = (s - IN2SLOTS) * 256 + lane * 4;
            int ly_ = F >> 9;
            int c   = (F >> 7) & 3;
            int x   = F & 127;
            gsrc[it] = in1b + (size_t)c * HW + (size_t)(y0 + ly_) * WW + x;
        }
    }

    float acc[ND][8];
    #pragma unroll
    for (int d = 0; d < ND; ++d)
        #pragma unroll
        for (int i = 0; i < 8; ++i) acc[d][i] = 0.0f;

    // ---- prologue: DMA chunk 0 into buffer 0 ----
    #pragma unroll
    for (int it = 0; it < 5; ++it)
        dma16(gsrc[it], &s2[0][(wv + it * 5) * 256]);
    #pragma unroll
    for (int it = 0; it < 5; ++it) gsrc[it] += CC * HW;
    __syncthreads();

    #pragma unroll 1
    for (int k = 0; k < NCHUNK; ++k) {
        const int p = k & 1;

        // DMA chunk k+1 (in flight across this chunk's compute)
        if (k + 1 < NCHUNK) {
            #pragma unroll
            for (int it = 0; it < 5; ++it)
                dma16(gsrc[it], &s2[1 - p][(wv + it * 5) * 256]);
            #pragma unroll
            for (int it = 0; it < 5; ++it) gsrc[it] += CC * HW;
        }

        // ---- compute chunk k ----
        #pragma unroll
        for (int cc = 0; cc < CC; ++cc) {
            const float* sp = &s2[p][cc * CPC + rl * PITCH + xg * 8];
            float4 wlo = *(const float4*)(sp);
            float4 whi = *(const float4*)(sp + 4);
            float w[8] = {wlo.x, wlo.y, wlo.z, wlo.w,
                          whi.x, whi.y, whi.z, whi.w};

            float W[16];
            W[0]  = dpp_shr1(w[4]);   // x-4 from lane-1; 0 at image edge
            W[1]  = dpp_shr1(w[5]);
            W[2]  = dpp_shr1(w[6]);
            W[3]  = dpp_shr1(w[7]);
            #pragma unroll
            for (int i = 0; i < 8; ++i) W[4 + i] = w[i];
            W[12] = dpp_shl1(w[0]);   // x+8 from lane+1; 0 at image edge
            W[13] = dpp_shl1(w[1]);
            W[14] = dpp_shl1(w[2]);
            W[15] = dpp_shl1(w[3]);

            const float* apx = &s2[p][IN1OFF + (ly * CC + cc) * 128 + xg * 8];
            float4 a0 = *(const float4*)(apx);
            float4 a1 = *(const float4*)(apx + 4);
            float a[8] = {a0.x, a0.y, a0.z, a0.w, a1.x, a1.y, a1.z, a1.w};

            #pragma unroll
            for (int d = 0; d < ND; ++d)
                #pragma unroll
                for (int i = 0; i < 8; ++i)
                    acc[d][i] = fmaf(a[i], W[i + d], acc[d][i]);
        }
        __syncthreads();   // also drains DMA for chunk k+1 (vmcnt(0))
    }

    // ---- epilogue: mean over C; OOB rows scale to exact zero ----
    if (act) {
        const float sc = rok ? (1.0f / (float)CH) : 0.0f;
        float* outb = out + (size_t)b * NDISP * HW
                          + (size_t)(y0 + ly) * WW + xg * 8;
        #pragma unroll
        for (int d = 0; d < ND; ++d) {
            float* op = outb + (size_t)(dy * ND + d) * HW;
            float4 v0 = make_float4(acc[d][0] * sc, acc[d][1] * sc,
                                    acc[d][2] * sc, acc[d][3] * sc);
            float4 v1 = make_float4(acc[d][4] * sc, acc[d][5] * sc,
                                    acc[d][6] * sc, acc[d][7] * sc);
            *(float4*)(op)     = v0;
            *(float4*)(op + 4) = v1;
        }
    }
}

extern "C" void kernel_launch(void* const* d_in, const int* in_sizes, int n_in,
                              void* d_out, int out_size, void* d_ws, size_t ws_size,
                              hipStream_t stream) {
    const float* in1 = (const float*)d_in[0];
    const float* in2 = (const float*)d_in[1];
    float* out = (float*)d_out;
    dim3 grid(BATCH, HH / TY);
    corr_kernel<<<grid, NT, 0, stream>>>(in1, in2, out);
}

// Round 7
// 201.045 us; speedup vs baseline: 1.1437x; 1.1437x over previous
//
#include <hip/hip_runtime.h>

// Correlation / cost-volume, fp32.
// corr[b, dy*9+dx, y, x] = (1/128) * sum_c in1[b,c,y,x] * in2[b,c,y+dy-4,x+dx-4]
//
// R7: co-residency fix. Evidence R1-R6: blocks with ~51 KB LDS never
// co-reside (occupancy == 1 block/CU in every round) => effective LDS
// scheduling pool ~64 KB, not 160 KB. This version needs 28.7 KB/block:
//   CC=2 channels/chunk (64 chunks), TY=2, in1+in2 both via global_load_lds
//   DMA (no register-destination global loads anywhere in the hot loop),
//   all LDS regions pitched 132 (R6's in1 pitch-128 caused 2.6M conflicts).
// Grid 512 = 2 blocks/CU: two independent barrier domains overlap each
// other's DMA drains. Inner loop unchanged from R5/R6 (DPP x-halos,
// 2 ds_read_b128 + 72 FMA per thread-channel).

#define MAXD 4
#define ND 9
#define NDISP 81
#define BATCH 8
#define CH 128
#define HH 128
#define WW 128
#define HW (HH * WW)
#define CC 2                      // channels per chunk
#define NCHUNK (CH / CC)          // 64
#define TY 2
#define NROW (TY + 2 * MAXD)      // 10 staged in2 rows
#define PITCH 132                 // 128 px + 4 pad floats (banks)
#define CPC2 (NROW * PITCH)       // 1320 floats per in2 channel
#define IN2F (CC * CPC2)          // 2640 floats in2 per chunk
#define IN2SLOTS 11               // ceil(2640/256)
#define IN1OFF (IN2SLOTS * 256)   // 2816: in1 region base
#define CPL1 (CC * PITCH)         // 264 floats per in1 row
#define IN1F (TY * CPL1)          // 528 floats in1 per chunk
#define NSLOT 14                  // 11 in2 + 3 in1 1-KB DMA slots
#define BUFF (NSLOT * 256)        // 3584 floats per buffer (14336 B)
#define NT 320                    // 5 waves; threads 0..287 compute
#define NACT 288                  // (ly:2)(dy:9)(xg:16)

typedef const __attribute__((address_space(1))) float GAS;
typedef __attribute__((address_space(3))) float LAS;

__device__ __forceinline__ void dma16(const float* g, float* l) {
    __builtin_amdgcn_global_load_lds((GAS*)g, (LAS*)l, 16, 0, 0);
}
__device__ __forceinline__ float dpp_shr1(float x) {   // lane i <- lane i-1
    return __int_as_float(__builtin_amdgcn_update_dpp(
        0, __float_as_int(x), 0x111, 0xF, 0xF, true));
}
__device__ __forceinline__ float dpp_shl1(float x) {   // lane i <- lane i+1
    return __int_as_float(__builtin_amdgcn_update_dpp(
        0, __float_as_int(x), 0x101, 0xF, 0xF, true));
}

__global__ __launch_bounds__(NT, 2) void corr_kernel(
    const float* __restrict__ in1,
    const float* __restrict__ in2,
    float* __restrict__ out)
{
    __shared__ float s2[2][BUFF];   // 2 x 14336 B = 28672 B

    const int tid = threadIdx.x;
    const int b   = blockIdx.x;
    const int y0  = blockIdx.y * TY;

    const bool act = tid < NACT;
    const int xg   = tid & 15;              // 16 lanes span the 128-px row
    const int dy   = (tid >> 4) % ND;
    const int ly   = act ? (tid / 144) : 0; // pad threads use valid addrs
    const int lane = tid & 63;
    const int rl   = ly + dy;               // staged in2 row consumed
    const bool rok = (unsigned)(y0 + rl - MAXD) < (unsigned)HH;

    const float* in1b = in1 + (size_t)b * CH * HW;
    const float* in2b = in2 + (size_t)b * CH * HW;

    // ---- DMA slot sources: 3 slots/wave, slot s = wv + it*5 ----
    const int wv = __builtin_amdgcn_readfirstlane(tid >> 6);   // 0..4
    const float* gsrc[3];
    bool use[3];
    int ldsoff[3];
    #pragma unroll
    for (int it = 0; it < 3; ++it) {
        int s   = wv + it * 5;
        use[it] = (s < NSLOT);
        int ss  = use[it] ? s : 0;
        ldsoff[it] = ss * 256;
        if (ss < IN2SLOTS) {
            // in2 region: flat F -> [c][R][132]
            int F = ss * 256 + lane * 4;
            int c = F / CPC2;
            int f = F - c * CPC2;
            int R = f / PITCH;
            int j = f - R * PITCH;          // 16B chunks: j in {0,4,...,128}
            bool v = (c < CC) && (j < WW);
            int rr = y0 - MAXD + R;
            int sr = rr < 0 ? 0 : (rr >= HH ? HH - 1 : rr);  // garbage OK
            gsrc[it] = in2b + (v ? ((size_t)c * HW + (size_t)sr * WW + j) : 0);
        } else {
            // in1 region: flat F -> [ly][c][132]
            int F   = (ss - IN2SLOTS) * 256 + lane * 4;
            bool v  = F < IN1F;
            int Fc  = v ? F : 0;
            int ly_ = Fc / CPL1;
            int rem = Fc - ly_ * CPL1;
            int c   = rem / PITCH;
            int j   = rem - c * PITCH;
            v = v && (j < WW);
            gsrc[it] = in1b + (v ? ((size_t)c * HW + (size_t)(y0 + ly_) * WW + j) : 0);
        }
    }

    float acc[ND][8];
    #pragma unroll
    for (int d = 0; d < ND; ++d)
        #pragma unroll
        for (int i = 0; i < 8; ++i) acc[d][i] = 0.0f;

    // ---- prologue: DMA chunk 0 into buffer 0 ----
    #pragma unroll
    for (int it = 0; it < 3; ++it)
        if (use[it]) dma16(gsrc[it], &s2[0][ldsoff[it]]);
    #pragma unroll
    for (int it = 0; it < 3; ++it) gsrc[it] += CC * HW;
    __syncthreads();

    #pragma unroll 1
    for (int k = 0; k < NCHUNK; ++k) {
        const int p = k & 1;

        // DMA chunk k+1 (ages across this chunk's compute)
        if (k + 1 < NCHUNK) {
            #pragma unroll
            for (int it = 0; it < 3; ++it)
                if (use[it]) dma16(gsrc[it], &s2[1 - p][ldsoff[it]]);
            #pragma unroll
            for (int it = 0; it < 3; ++it) gsrc[it] += CC * HW;
        }

        // ---- compute chunk k ----
        #pragma unroll
        for (int cc = 0; cc < CC; ++cc) {
            const float* sp = &s2[p][cc * CPC2 + rl * PITCH + xg * 8];
            float4 wlo = *(const float4*)(sp);
            float4 whi = *(const float4*)(sp + 4);
            float w[8] = {wlo.x, wlo.y, wlo.z, wlo.w,
                          whi.x, whi.y, whi.z, whi.w};

            float W[16];
            W[0]  = dpp_shr1(w[4]);   // x-4 from lane-1; 0 at image edge
            W[1]  = dpp_shr1(w[5]);
            W[2]  = dpp_shr1(w[6]);
            W[3]  = dpp_shr1(w[7]);
            #pragma unroll
            for (int i = 0; i < 8; ++i) W[4 + i] = w[i];
            W[12] = dpp_shl1(w[0]);   // x+8 from lane+1; 0 at image edge
            W[13] = dpp_shl1(w[1]);
            W[14] = dpp_shl1(w[2]);
            W[15] = dpp_shl1(w[3]);

            const float* apx = &s2[p][IN1OFF + ly * CPL1 + cc * PITCH + xg * 8];
            float4 a0 = *(const float4*)(apx);
            float4 a1 = *(const float4*)(apx + 4);
            float a[8] = {a0.x, a0.y, a0.z, a0.w, a1.x, a1.y, a1.z, a1.w};

            #pragma unroll
            for (int d = 0; d < ND; ++d)
                #pragma unroll
                for (int i = 0; i < 8; ++i)
                    acc[d][i] = fmaf(a[i], W[i + d], acc[d][i]);
        }
        __syncthreads();   // drains DMA for chunk k+1; other block covers
    }

    // ---- epilogue: mean over C; OOB rows scale to exact zero ----
    if (act) {
        const float sc = rok ? (1.0f / (float)CH) : 0.0f;
        float* outb = out + (size_t)b * NDISP * HW
                          + (size_t)(y0 + ly) * WW + xg * 8;
        #pragma unroll
        for (int d = 0; d < ND; ++d) {
            float* op = outb + (size_t)(dy * ND + d) * HW;
            float4 v0 = make_float4(acc[d][0] * sc, acc[d][1] * sc,
                                    acc[d][2] * sc, acc[d][3] * sc);
            float4 v1 = make_float4(acc[d][4] * sc, acc[d][5] * sc,
                                    acc[d][6] * sc, acc[d][7] * sc);
            *(float4*)(op)     = v0;
            *(float4*)(op + 4) = v1;
        }
    }
}

extern "C" void kernel_launch(void* const* d_in, const int* in_sizes, int n_in,
                              void* d_out, int out_size, void* d_ws, size_t ws_size,
                              hipStream_t stream) {
    const float* in1 = (const float*)d_in[0];
    const float* in2 = (const float*)d_in[1];
    float* out = (float*)d_out;
    dim3 grid(BATCH, HH / TY);
    corr_kernel<<<grid, NT, 0, stream>>>(in1, in2, out);
}